// Round 7
// baseline (347.389 us; speedup 1.0000x reference)
//
#include <hip/hip_runtime.h>
#include <math.h>

typedef unsigned short u16;
typedef unsigned int   u32;

#define NB     32768   // batch rows
#define ND     512     // d_in
#define NM     2048    // memory slots
#define TAUINV 10.0f
#define FBETA  10.0f
#define FTHETA 0.5f
#define FGAMMA 0.5f
#define CMAX   32      // candidate cap per row
#define MARGIN 3e-3f   // covers bf16-gemm err + bf16-S rounding

typedef __bf16 bf16x8 __attribute__((ext_vector_type(8)));
typedef float  f32x4  __attribute__((ext_vector_type(4)));

__device__ __forceinline__ u16 f2bf(float x) {
    u32 b = __float_as_uint(x);
    u32 r = (b + 0x7FFFu + ((b >> 16) & 1u)) >> 16;   // RNE
    return (u16)r;
}
__device__ __forceinline__ float bf2f(u32 h) { return __uint_as_float(h << 16); }

// ---------------- x rows: L2-normalize (f32 -> bf16) ----------------
__global__ __launch_bounds__(256) void rownorm_kernel(const float* __restrict__ in,
                                                      u16* __restrict__ out) {
    int row  = blockIdx.x * 4 + (threadIdx.x >> 6);
    int lane = threadIdx.x & 63;
    const float4* p = (const float4*)(in + (size_t)row * ND);
    float4 a = p[lane * 2], b = p[lane * 2 + 1];
    float ss = a.x*a.x + a.y*a.y + a.z*a.z + a.w*a.w +
               b.x*b.x + b.y*b.y + b.z*b.z + b.w*b.w;
    #pragma unroll
    for (int off = 1; off < 64; off <<= 1) ss += __shfl_xor(ss, off, 64);
    float sc = 1.0f / fmaxf(sqrtf(ss), 1e-12f);
    uint4 o;
    o.x = (u32)f2bf(a.x*sc) | ((u32)f2bf(a.y*sc) << 16);
    o.y = (u32)f2bf(a.z*sc) | ((u32)f2bf(a.w*sc) << 16);
    o.z = (u32)f2bf(b.x*sc) | ((u32)f2bf(b.y*sc) << 16);
    o.w = (u32)f2bf(b.z*sc) | ((u32)f2bf(b.w*sc) << 16);
    ((uint4*)(out + (size_t)row * ND))[lane] = o;
}

// ---------------- K rows: bf16-normalize + fp64 inv-norm + logs + counts=0 ----------------
__global__ __launch_bounds__(256) void kprep_kernel(const float* __restrict__ K,
        u16* __restrict__ kn, double* __restrict__ invKn,
        const float* __restrict__ s, float* __restrict__ logs, float* __restrict__ counts) {
    int row  = blockIdx.x * 4 + (threadIdx.x >> 6);
    int lane = threadIdx.x & 63;
    const float4* p = (const float4*)(K + (size_t)row * ND);
    float4 a = p[lane * 2], b = p[lane * 2 + 1];
    double ss = (double)a.x*a.x + (double)a.y*a.y + (double)a.z*a.z + (double)a.w*a.w +
                (double)b.x*b.x + (double)b.y*b.y + (double)b.z*b.z + (double)b.w*b.w;
    #pragma unroll
    for (int off = 1; off < 64; off <<= 1) ss += __shfl_xor(ss, off, 64);
    double inv = 1.0 / fmax(sqrt(ss), 1e-12);
    float sc = (float)inv;
    uint4 o;
    o.x = (u32)f2bf(a.x*sc) | ((u32)f2bf(a.y*sc) << 16);
    o.y = (u32)f2bf(a.z*sc) | ((u32)f2bf(a.w*sc) << 16);
    o.z = (u32)f2bf(b.x*sc) | ((u32)f2bf(b.y*sc) << 16);
    o.w = (u32)f2bf(b.z*sc) | ((u32)f2bf(b.w*sc) << 16);
    ((uint4*)(kn + (size_t)row * ND))[lane] = o;
    if (lane == 0) {
        invKn[row]  = inv;
        logs[row]   = logf(s[row] + 1e-8f);
        counts[row] = 0.0f;
    }
}

// ---------------- GEMM: 256x256 tile, 8-wave, 8-phase lockstep, swizzled LDS ----------------
#define GLDS(SRC, OFF) __builtin_amdgcn_global_load_lds( \
    (const __attribute__((address_space(1))) void*)(SRC), \
    (__attribute__((address_space(3))) void*)(smem_c + (OFF)), 16, 0, 0)

#define STAGE8(KTN, D) { \
    _Pragma("unroll") for (int u_ = 0; u_ < 4; ++u_) { \
        _Pragma("unroll") for (int i_ = 0; i_ < 2; ++i_) { \
            int li_ = i_ * 512 + tid; \
            int rl_ = li_ >> 3; \
            int kb_ = ((li_ & 7) * 16) ^ ((rl_ & 7) << 4); \
            const char* src_ = (u_ < 2) \
                ? (const char*)Xn + (((size_t)(rowA + u_ * 128 + rl_)) << 10) + (KTN) * 128 + kb_ \
                : (const char*)Kn + (((size_t)(colB + (u_ - 2) * 128 + rl_)) << 10) + (KTN) * 128 + kb_; \
            GLDS(src_, (u_ < 2 ? 0 : 65536) + (D) * 32768 + (u_ & 1) * 16384 + li_ * 16); \
        } \
    } \
}

#define PHASE(AOFF, BOFF, P) { \
    const int ks_ = (P) >> 1, m4_ = ((P) & 1) * 4; \
    if (((P) & 1) == 0) { \
        _Pragma("unroll") for (int n_ = 0; n_ < 4; ++n_) \
            bq[n_] = *(const bf16x8*)(smem_c + (BOFF) + \
                ((wcl * 64 + n_ * 16 + lo) * 128) + ((ks_ * 64 + hb) ^ swzc)); \
    } \
    _Pragma("unroll") for (int mm_ = 0; mm_ < 4; ++mm_) \
        af[mm_] = *(const bf16x8*)(smem_c + (AOFF) + \
            (((m4_ + mm_) * 16 + lo) * 128) + ((ks_ * 64 + hb) ^ swzc)); \
    __builtin_amdgcn_s_barrier(); \
    __builtin_amdgcn_sched_barrier(0); \
    asm volatile("s_waitcnt lgkmcnt(0)" ::: "memory"); \
    __builtin_amdgcn_sched_barrier(0); \
    __builtin_amdgcn_s_setprio(1); \
    _Pragma("unroll") for (int mm_ = 0; mm_ < 4; ++mm_) \
        _Pragma("unroll") for (int n_ = 0; n_ < 4; ++n_) \
            acc[m4_ + mm_][n_] = __builtin_amdgcn_mfma_f32_16x16x32_bf16( \
                af[mm_], bq[n_], acc[m4_ + mm_][n_], 0, 0, 0); \
    __builtin_amdgcn_s_setprio(0); \
    __builtin_amdgcn_sched_barrier(0); \
    __builtin_amdgcn_s_barrier(); \
    __builtin_amdgcn_sched_barrier(0); \
}

#define TILE(KT, CUR, LASTVM, DOSTAGE) { \
    if (LASTVM) { asm volatile("s_waitcnt vmcnt(0)" ::: "memory"); } \
    else        { asm volatile("s_waitcnt vmcnt(8)" ::: "memory"); } \
    __builtin_amdgcn_s_barrier(); \
    __builtin_amdgcn_sched_barrier(0); \
    bf16x8 af[4], bq[4]; \
    const int aO_ = (CUR) * 32768 + wr * 16384; \
    const int bO_ = 65536 + (CUR) * 32768 + bh * 16384; \
    PHASE(aO_, bO_, 0) \
    PHASE(aO_, bO_, 1) \
    PHASE(aO_, bO_, 2) \
    PHASE(aO_, bO_, 3) \
    if (DOSTAGE) STAGE8((KT) + 2, CUR); \
}

__global__ __launch_bounds__(512, 2) void gemm_kernel(const u16* __restrict__ Xn,
                                                      const u16* __restrict__ Kn,
                                                      u16* __restrict__ S2) {
    __shared__ u16 smem[65536];   // 128 KiB
    char* smem_c = (char*)smem;
    const int tid  = threadIdx.x;
    const int lane = tid & 63;
    const int wid  = tid >> 6;          // 0..7
    const int wr   = wid >> 2;          // 0..1  (M)
    const int wc   = wid & 3;           // 0..3  (N)
    const int wcl  = wc & 1;
    const int bh   = wc >> 1;
    const int lo   = lane & 15;
    const int hb   = (lane >> 4) * 16;  // k-slot byte within 64B k-slice
    const int swzc = (lo & 7) << 4;

    int lin = blockIdx.x;
    int swz = (lin & 7) * 128 + (lin >> 3);
    const int rowA = (swz >> 3) * 256;   // 128 row-panels
    const int colB = (swz & 7) * 256;    // 8 col-panels

    f32x4 acc[8][4];
    #pragma unroll
    for (int m = 0; m < 8; m++)
        #pragma unroll
        for (int n = 0; n < 4; n++) acc[m][n] = (f32x4){0.f, 0.f, 0.f, 0.f};

    STAGE8(0, 0);   // K-tile 0 -> buf0 (8 loads)
    STAGE8(1, 1);   // K-tile 1 -> buf1 (8 loads)

    for (int kt2 = 0; kt2 < 6; kt2 += 2) {
        TILE(kt2,     0, 0, 1)
        TILE(kt2 + 1, 1, 0, 1)
    }
    TILE(6, 0, 0, 0)
    TILE(7, 1, 1, 0)

    // epilogue: repack 256x256 fp32 acc -> bf16 via LDS, two 128-row passes
    u16* St = smem;                      // [128][264] u16 (row stride 528 B, 16B-aligned)
    #pragma unroll
    for (int h = 0; h < 2; ++h) {
        __syncthreads();
        if (wr == h) {
            #pragma unroll
            for (int m = 0; m < 8; m++) {
                int rloc = m * 16 + (lane >> 4) * 4;
                #pragma unroll
                for (int n = 0; n < 4; n++) {
                    int cloc = wc * 64 + n * 16 + lo;
                    #pragma unroll
                    for (int j = 0; j < 4; j++)
                        St[(rloc + j) * 264 + cloc] = f2bf(acc[m][n][j]);
                }
            }
        }
        __syncthreads();
        #pragma unroll
        for (int jj = 0; jj < 8; ++jj) {
            int idx = jj * 512 + tid;         // 0..4095
            int r = idx >> 5, sl = idx & 31;
            uint4 v = *(const uint4*)(St + (size_t)r * 264 + sl * 8);
            *(uint4*)(S2 + (size_t)(rowA + h * 128 + r) * NM + colB + sl * 8) = v;
        }
    }
}

// ---------------- fused candidate-select + 4-way-parallel fp64 refine ----------------
#define INS(VV) { float x_ = (VV); float h_;                      \
    h_ = fmaxf(t0, x_); x_ = fminf(t0, x_); t0 = h_;              \
    h_ = fmaxf(t1, x_); x_ = fminf(t1, x_); t1 = h_;              \
    h_ = fmaxf(t2, x_); x_ = fminf(t2, x_); t2 = h_;              \
    h_ = fmaxf(t3, x_); x_ = fminf(t3, x_); t3 = h_;              \
    h_ = fmaxf(t4, x_); x_ = fminf(t4, x_); t4 = h_;              \
    h_ = fmaxf(t5, x_); x_ = fminf(t5, x_); t5 = h_;              \
    h_ = fmaxf(t6, x_); x_ = fminf(t6, x_); t6 = h_;              \
    h_ = fmaxf(t7, x_); x_ = fminf(t7, x_); t7 = h_; }

#define ROUND(G) {                                                \
    float mv = t0;                                                \
    mv = fmaxf(mv, __shfl_xor(mv, 1, 64));                        \
    mv = fmaxf(mv, __shfl_xor(mv, 2, 64));                        \
    mv = fmaxf(mv, __shfl_xor(mv, 4, 64));                        \
    mv = fmaxf(mv, __shfl_xor(mv, 8, 64));                        \
    mv = fmaxf(mv, __shfl_xor(mv, 16, 64));                       \
    mv = fmaxf(mv, __shfl_xor(mv, 32, 64));                       \
    G = mv;                                                       \
    bool pop = (t0 == mv);                                        \
    t0 = pop ? t1 : t0; t1 = pop ? t2 : t1; t2 = pop ? t3 : t2;   \
    t3 = pop ? t4 : t3; t4 = pop ? t5 : t4; t5 = pop ? t6 : t5;   \
    t6 = pop ? t7 : t6; t7 = pop ? -__builtin_inff() : t7; }

// LDS x-row swizzle (float index): XOR bits[4:2] with bits[7:5] -> breaks the
// 16-way bank conflict of stride-128B reads; bijective, float4-aligned.
#define XSWZ(F) ((F) ^ ((((F) >> 5) & 7) << 2))

__global__ __launch_bounds__(256) void candrefine_kernel(const u16* __restrict__ S2,
        const float* __restrict__ x, const float* __restrict__ K,
        const double* __restrict__ invKn,
        float* __restrict__ top8v, u16* __restrict__ top8i,
        float* __restrict__ f_out, float* __restrict__ g_out, float* __restrict__ counts) {
    __shared__ float xl[4][512];
    __shared__ u16 candl[4][CMAX];
    __shared__ int scnt[4];
    int w    = threadIdx.x >> 6;
    int lane = threadIdx.x & 63;
    int row  = blockIdx.x * 4 + w;
    if (lane == 0) scnt[w] = 0;

    // stage x row into LDS (swizzled) early; latency hides under phase A
    {
        const float4* xr = (const float4*)(x + (size_t)row * ND);
        float4 a = xr[lane * 2], b = xr[lane * 2 + 1];
        *(float4*)&xl[w][XSWZ(lane * 8)]     = a;
        *(float4*)&xl[w][XSWZ(lane * 8 + 4)] = b;
    }

    // ---- phase A: candidate selection from bf16 S (wave-local) ----
    {
        const uint4* p = (const uint4*)(S2 + (size_t)row * NM);
        uint4 v[4];
        float t0 = -__builtin_inff(), t1 = t0, t2 = t0, t3 = t0, t4 = t0, t5 = t0, t6 = t0, t7 = t0;
        #pragma unroll
        for (int it = 0; it < 4; ++it) {
            v[it] = p[it * 64 + lane];
            const u32* d = (const u32*)&v[it];
            #pragma unroll
            for (int j = 0; j < 4; ++j) {
                INS(bf2f(d[j] & 0xFFFFu));
                INS(bf2f(d[j] >> 16));
            }
        }
        float g0, g1, g2, g3, g4, g5, g6, g7;
        ROUND(g0); ROUND(g1); ROUND(g2); ROUND(g3);
        ROUND(g4); ROUND(g5); ROUND(g6); ROUND(g7);
        (void)g0; (void)g1; (void)g2; (void)g3; (void)g4; (void)g5; (void)g6;
        float T = g7 - MARGIN;   // dup-pops only lower T -> safe (more candidates)

        #pragma unroll
        for (int it = 0; it < 4; ++it) {
            const u32* d = (const u32*)&v[it];
            #pragma unroll
            for (int j = 0; j < 4; ++j) {
                float flo = bf2f(d[j] & 0xFFFFu);
                float fhi = bf2f(d[j] >> 16);
                int   col = it * 512 + lane * 8 + j * 2;
                if (flo >= T) {
                    int pos = atomicAdd(&scnt[w], 1);
                    if (pos < CMAX) candl[w][pos] = (u16)col;
                }
                if (fhi >= T) {
                    int pos = atomicAdd(&scnt[w], 1);
                    if (pos < CMAX) candl[w][pos] = (u16)(col + 1);
                }
            }
        }
    }
    asm volatile("s_waitcnt lgkmcnt(0)" ::: "memory");

    // ---- phase B: fp64 rescore, 4 candidates in parallel (16-lane groups) ----
    const int sub = lane & 15;           // position within group
    const int grp = lane >> 4;           // group id 0..3

    float xv[32];
    #pragma unroll
    for (int i = 0; i < 8; i++) {
        float4 t = *(const float4*)(&xl[w][XSWZ(sub * 32 + i * 4)]);
        xv[4*i] = t.x; xv[4*i+1] = t.y; xv[4*i+2] = t.z; xv[4*i+3] = t.w;
    }
    double ss = 0.0;
    #pragma unroll
    for (int i = 0; i < 32; i++) ss = fma((double)xv[i], (double)xv[i], ss);
    ss += __shfl_xor(ss, 1, 64); ss += __shfl_xor(ss, 2, 64);
    ss += __shfl_xor(ss, 4, 64); ss += __shfl_xor(ss, 8, 64);
    double xinv = 1.0 / fmax(sqrt(ss), 1e-12);

    int cnt = min(scnt[w], CMAX);        // always >= 8 (T < g7 guarantees 8 survivors)
    double myval = -1e300; int myidx = 0;
    int nb = (cnt + 3) >> 2;
    for (int b = 0; b < nb; ++b) {
        int c  = b * 4 + grp;
        int ci = (c < cnt) ? (int)candl[w][c] : 0;
        const float4* kr = (const float4*)(K + (size_t)ci * ND + sub * 32);
        double acc = 0.0;
        #pragma unroll
        for (int i = 0; i < 8; i++) {
            float4 kk = kr[i];
            acc = fma((double)xv[4*i],   (double)kk.x, acc);
            acc = fma((double)xv[4*i+1], (double)kk.y, acc);
            acc = fma((double)xv[4*i+2], (double)kk.z, acc);
            acc = fma((double)xv[4*i+3], (double)kk.w, acc);
        }
        acc += __shfl_xor(acc, 1, 64); acc += __shfl_xor(acc, 2, 64);
        acc += __shfl_xor(acc, 4, 64); acc += __shfl_xor(acc, 8, 64);
        double val = acc * xinv * invKn[ci];
        // route candidate c to owner lane L = c (source: lane (L&3)*16)
        double gv = __shfl(val, (lane & 3) << 4, 64);
        int    gi = __shfl(ci,  (lane & 3) << 4, 64);
        if ((lane >> 2) == b && lane < cnt) { myval = gv; myidx = gi; }
    }

    float vals[8]; int idxs[8];
    #pragma unroll
    for (int r = 0; r < 8; ++r) {
        double m = myval;
        #pragma unroll
        for (int off = 1; off < 64; off <<= 1) m = fmax(m, __shfl_xor(m, off, 64));
        unsigned long long bal = __ballot(myval == m);
        int wl = __ffsll(bal) - 1;
        int wi = __shfl(myidx, wl, 64);
        vals[r] = (float)m;
        idxs[r] = wi;
        if (lane == wl) myval = -1e300;
    }

    if (lane == 0) {
        float fv = vals[0];
        f_out[row] = fv;
        g_out[row] = 1.0f / (1.0f + expf(FBETA * (fv - FTHETA)));
        atomicAdd(&counts[idxs[0]], 1.0f);
        float4* tv = (float4*)(top8v + (size_t)row * 8);
        tv[0] = (float4){vals[0], vals[1], vals[2], vals[3]};
        tv[1] = (float4){vals[4], vals[5], vals[6], vals[7]};
        uint4 ip;
        ip.x = (u32)idxs[0] | ((u32)idxs[1] << 16);
        ip.y = (u32)idxs[2] | ((u32)idxs[3] << 16);
        ip.z = (u32)idxs[4] | ((u32)idxs[5] << 16);
        ip.w = (u32)idxs[6] | ((u32)idxs[7] << 16);
        *(uint4*)(top8i + (size_t)row * 8) = ip;
    }
}

// ---------------- finalize: softmax(8), attn row (zeros+scatter), y = g * attn@V ----------------
__global__ __launch_bounds__(256) void finalize_kernel(const float* __restrict__ top8v,
        const u16* __restrict__ top8i, const float* __restrict__ counts,
        const float* __restrict__ logs, const float* __restrict__ V,
        const float* __restrict__ g_out, float* __restrict__ y, float* __restrict__ attn) {
    int row  = blockIdx.x * 4 + (threadIdx.x >> 6);
    int lane = threadIdx.x & 63;
    float4 z = {0.f, 0.f, 0.f, 0.f};
    float4* arow = (float4*)(attn + (size_t)row * NM);
    #pragma unroll
    for (int i = 0; i < 8; i++) arow[i * 64 + lane] = z;

    float logit = -__builtin_inff();
    int idx = 0;
    if (lane < 8) {
        idx = (int)top8i[(size_t)row * 8 + lane];
        float val = top8v[(size_t)row * 8 + lane];
        logit = val * TAUINV + logs[idx] - (FGAMMA / (float)NB) * counts[idx];
    }
    float mv = logit;
    mv = fmaxf(mv, __shfl_xor(mv, 1, 64));
    mv = fmaxf(mv, __shfl_xor(mv, 2, 64));
    mv = fmaxf(mv, __shfl_xor(mv, 4, 64));
    float e = (lane < 8) ? expf(logit - mv) : 0.0f;
    float sum = e;
    sum += __shfl_xor(sum, 1, 64);
    sum += __shfl_xor(sum, 2, 64);
    sum += __shfl_xor(sum, 4, 64);
    float w = e / sum;   // garbage on lanes >=8, never consumed

    asm volatile("s_waitcnt vmcnt(0)" ::: "memory");
    if (lane < 8) attn[(size_t)row * NM + idx] = w;

    float4 acc0 = z, acc1 = z;
    #pragma unroll
    for (int j = 0; j < 8; j++) {
        float wj = __shfl(w, j, 64);
        int   ij = __shfl(idx, j, 64);
        const float4* vr = (const float4*)(V + (size_t)ij * 512);
        float4 v0 = vr[lane * 2], v1 = vr[lane * 2 + 1];
        acc0.x += wj * v0.x; acc0.y += wj * v0.y; acc0.z += wj * v0.z; acc0.w += wj * v0.w;
        acc1.x += wj * v1.x; acc1.y += wj * v1.y; acc1.z += wj * v1.z; acc1.w += wj * v1.w;
    }
    float gr = g_out[row];
    float4 o0 = {gr * acc0.x, gr * acc0.y, gr * acc0.z, gr * acc0.w};
    float4 o1 = {gr * acc1.x, gr * acc1.y, gr * acc1.z, gr * acc1.w};
    float4* yp = (float4*)(y + (size_t)row * 512);
    yp[lane * 2]     = o0;
    yp[lane * 2 + 1] = o1;
}

extern "C" void kernel_launch(void* const* d_in, const int* in_sizes, int n_in,
                              void* d_out, int out_size, void* d_ws, size_t ws_size,
                              hipStream_t stream) {
    const float* x = (const float*)d_in[0];
    const float* K = (const float*)d_in[1];
    const float* V = (const float*)d_in[2];
    const float* s = (const float*)d_in[3];

    float* y     = (float*)d_out;                       // [32768][512]
    float* f_out = y + (size_t)NB * 512;                // [32768]
    float* g_out = f_out + NB;                          // [32768]
    float* attn  = g_out + NB;                          // [32768][2048]

    char* ws = (char*)d_ws;
    u16*    xn     = (u16*)ws;                          // 33,554,432 B
    u16*    kn     = (u16*)(ws + 33554432);             //  2,097,152 B -> 35,651,584
    float*  logs   = (float*)(ws + 35651584);           //      8,192 B -> 35,659,776
    float*  counts = (float*)(ws + 35659776);           //      8,192 B -> 35,667,968
    double* invKn  = (double*)(ws + 35667968);          //     16,384 B -> 35,684,352
    float*  top8v  = (float*)(ws + 35684352);           //  1,048,576 B -> 36,732,928
    u16*    top8i  = (u16*)(ws + 36732928);             //    524,288 B -> 37,257,216
    u16*    S2     = (u16*)(ws + 67108864);             // 134,217,728 B bf16 scores

    rownorm_kernel<<<NB / 4, 256, 0, stream>>>(x, xn);
    kprep_kernel<<<NM / 4, 256, 0, stream>>>(K, kn, invKn, s, logs, counts);
    gemm_kernel<<<1024, 512, 0, stream>>>(xn, kn, S2);
    candrefine_kernel<<<NB / 4, 256, 0, stream>>>(S2, x, K, invKn,
                                                  top8v, top8i, f_out, g_out, counts);
    finalize_kernel<<<NB / 4, 256, 0, stream>>>(top8v, top8i, counts, logs, V,
                                                g_out, y, attn);
}

// Round 8
// 312.182 us; speedup vs baseline: 1.1128x; 1.1128x over previous
//
#include <hip/hip_runtime.h>
#include <math.h>

typedef unsigned short u16;
typedef unsigned int   u32;

#define NB     32768   // batch rows
#define ND     512     // d_in
#define NM     2048    // memory slots
#define TAUINV 10.0f
#define FBETA  10.0f
#define FTHETA 0.5f
#define FGAMMA 0.5f
#define CMAX   32      // candidate cap per row
#define MARGIN 3e-3f   // covers bf16-gemm err + bf16-S rounding

typedef __bf16 bf16x8 __attribute__((ext_vector_type(8)));
typedef float  f32x4  __attribute__((ext_vector_type(4)));

__device__ __forceinline__ u16 f2bf(float x) {
    u32 b = __float_as_uint(x);
    u32 r = (b + 0x7FFFu + ((b >> 16) & 1u)) >> 16;   // RNE
    return (u16)r;
}
__device__ __forceinline__ float bf2f(u32 h) { return __uint_as_float(h << 16); }

// ---------------- merged prep: x rows (f32 norm) + K rows (fp64 norm + side) ----------------
__global__ __launch_bounds__(256) void prep_kernel(const float* __restrict__ x,
        u16* __restrict__ xn, const float* __restrict__ K, u16* __restrict__ kn,
        double* __restrict__ invKn, const float* __restrict__ s,
        float* __restrict__ logs, float* __restrict__ counts) {
    int blk  = blockIdx.x;
    int w    = threadIdx.x >> 6;
    int lane = threadIdx.x & 63;
    if (blk < NB / 4) {                       // ---- x path ----
        int row = blk * 4 + w;
        const float4* p = (const float4*)(x + (size_t)row * ND);
        float4 a = p[lane * 2], b = p[lane * 2 + 1];
        float ss = a.x*a.x + a.y*a.y + a.z*a.z + a.w*a.w +
                   b.x*b.x + b.y*b.y + b.z*b.z + b.w*b.w;
        #pragma unroll
        for (int off = 1; off < 64; off <<= 1) ss += __shfl_xor(ss, off, 64);
        float sc = 1.0f / fmaxf(sqrtf(ss), 1e-12f);
        uint4 o;
        o.x = (u32)f2bf(a.x*sc) | ((u32)f2bf(a.y*sc) << 16);
        o.y = (u32)f2bf(a.z*sc) | ((u32)f2bf(a.w*sc) << 16);
        o.z = (u32)f2bf(b.x*sc) | ((u32)f2bf(b.y*sc) << 16);
        o.w = (u32)f2bf(b.z*sc) | ((u32)f2bf(b.w*sc) << 16);
        ((uint4*)(xn + (size_t)row * ND))[lane] = o;
    } else {                                  // ---- K path ----
        int row = (blk - NB / 4) * 4 + w;
        const float4* p = (const float4*)(K + (size_t)row * ND);
        float4 a = p[lane * 2], b = p[lane * 2 + 1];
        double ss = (double)a.x*a.x + (double)a.y*a.y + (double)a.z*a.z + (double)a.w*a.w +
                    (double)b.x*b.x + (double)b.y*b.y + (double)b.z*b.z + (double)b.w*b.w;
        #pragma unroll
        for (int off = 1; off < 64; off <<= 1) ss += __shfl_xor(ss, off, 64);
        double inv = 1.0 / fmax(sqrt(ss), 1e-12);
        float sc = (float)inv;
        uint4 o;
        o.x = (u32)f2bf(a.x*sc) | ((u32)f2bf(a.y*sc) << 16);
        o.y = (u32)f2bf(a.z*sc) | ((u32)f2bf(a.w*sc) << 16);
        o.z = (u32)f2bf(b.x*sc) | ((u32)f2bf(b.y*sc) << 16);
        o.w = (u32)f2bf(b.z*sc) | ((u32)f2bf(b.w*sc) << 16);
        ((uint4*)(kn + (size_t)row * ND))[lane] = o;
        if (lane == 0) {
            invKn[row]  = inv;
            logs[row]   = logf(s[row] + 1e-8f);
            counts[row] = 0.0f;
        }
    }
}

// ---------------- GEMM: 256x256 tile, 8-wave, 8-phase lockstep, swizzled LDS ----------------
#define GLDS(SRC, OFF) __builtin_amdgcn_global_load_lds( \
    (const __attribute__((address_space(1))) void*)(SRC), \
    (__attribute__((address_space(3))) void*)(smem_c + (OFF)), 16, 0, 0)

#define STAGE8(KTN, D) { \
    _Pragma("unroll") for (int u_ = 0; u_ < 4; ++u_) { \
        _Pragma("unroll") for (int i_ = 0; i_ < 2; ++i_) { \
            int li_ = i_ * 512 + tid; \
            int rl_ = li_ >> 3; \
            int kb_ = ((li_ & 7) * 16) ^ ((rl_ & 7) << 4); \
            const char* src_ = (u_ < 2) \
                ? (const char*)Xn + (((size_t)(rowA + u_ * 128 + rl_)) << 10) + (KTN) * 128 + kb_ \
                : (const char*)Kn + (((size_t)(colB + (u_ - 2) * 128 + rl_)) << 10) + (KTN) * 128 + kb_; \
            GLDS(src_, (u_ < 2 ? 0 : 65536) + (D) * 32768 + (u_ & 1) * 16384 + li_ * 16); \
        } \
    } \
}

#define PHASE(AOFF, BOFF, P) { \
    const int ks_ = (P) >> 1, m4_ = ((P) & 1) * 4; \
    if (((P) & 1) == 0) { \
        _Pragma("unroll") for (int n_ = 0; n_ < 4; ++n_) \
            bq[n_] = *(const bf16x8*)(smem_c + (BOFF) + \
                ((wcl * 64 + n_ * 16 + lo) * 128) + ((ks_ * 64 + hb) ^ swzc)); \
    } \
    _Pragma("unroll") for (int mm_ = 0; mm_ < 4; ++mm_) \
        af[mm_] = *(const bf16x8*)(smem_c + (AOFF) + \
            (((m4_ + mm_) * 16 + lo) * 128) + ((ks_ * 64 + hb) ^ swzc)); \
    __builtin_amdgcn_s_barrier(); \
    __builtin_amdgcn_sched_barrier(0); \
    asm volatile("s_waitcnt lgkmcnt(0)" ::: "memory"); \
    __builtin_amdgcn_sched_barrier(0); \
    __builtin_amdgcn_s_setprio(1); \
    _Pragma("unroll") for (int mm_ = 0; mm_ < 4; ++mm_) \
        _Pragma("unroll") for (int n_ = 0; n_ < 4; ++n_) \
            acc[m4_ + mm_][n_] = __builtin_amdgcn_mfma_f32_16x16x32_bf16( \
                af[mm_], bq[n_], acc[m4_ + mm_][n_], 0, 0, 0); \
    __builtin_amdgcn_s_setprio(0); \
    __builtin_amdgcn_sched_barrier(0); \
    __builtin_amdgcn_s_barrier(); \
    __builtin_amdgcn_sched_barrier(0); \
}

#define TILE(KT, CUR, LASTVM, DOSTAGE) { \
    if (LASTVM) { asm volatile("s_waitcnt vmcnt(0)" ::: "memory"); } \
    else        { asm volatile("s_waitcnt vmcnt(8)" ::: "memory"); } \
    __builtin_amdgcn_s_barrier(); \
    __builtin_amdgcn_sched_barrier(0); \
    bf16x8 af[4], bq[4]; \
    const int aO_ = (CUR) * 32768 + wr * 16384; \
    const int bO_ = 65536 + (CUR) * 32768 + bh * 16384; \
    PHASE(aO_, bO_, 0) \
    PHASE(aO_, bO_, 1) \
    PHASE(aO_, bO_, 2) \
    PHASE(aO_, bO_, 3) \
    if (DOSTAGE) STAGE8((KT) + 2, CUR); \
}

__global__ __launch_bounds__(512, 2) void gemm_kernel(const u16* __restrict__ Xn,
                                                      const u16* __restrict__ Kn,
                                                      u16* __restrict__ S2) {
    __shared__ u16 smem[65536];   // 128 KiB
    char* smem_c = (char*)smem;
    const int tid  = threadIdx.x;
    const int lane = tid & 63;
    const int wid  = tid >> 6;          // 0..7
    const int wr   = wid >> 2;          // 0..1  (M)
    const int wc   = wid & 3;           // 0..3  (N)
    const int wcl  = wc & 1;
    const int bh   = wc >> 1;
    const int lo   = lane & 15;
    const int hb   = (lane >> 4) * 16;  // k-slot byte within 64B k-slice
    const int swzc = (lo & 7) << 4;

    int lin = blockIdx.x;
    int swz = (lin & 7) * 128 + (lin >> 3);
    const int rowA = (swz >> 3) * 256;   // 128 row-panels
    const int colB = (swz & 7) * 256;    // 8 col-panels

    f32x4 acc[8][4];
    #pragma unroll
    for (int m = 0; m < 8; m++)
        #pragma unroll
        for (int n = 0; n < 4; n++) acc[m][n] = (f32x4){0.f, 0.f, 0.f, 0.f};

    STAGE8(0, 0);   // K-tile 0 -> buf0 (8 loads)
    STAGE8(1, 1);   // K-tile 1 -> buf1 (8 loads)

    for (int kt2 = 0; kt2 < 6; kt2 += 2) {
        TILE(kt2,     0, 0, 1)
        TILE(kt2 + 1, 1, 0, 1)
    }
    TILE(6, 0, 0, 0)
    TILE(7, 1, 1, 0)

    // epilogue: repack 256x256 fp32 acc -> bf16 via LDS, two 128-row passes
    u16* St = smem;                      // [128][264] u16 (row stride 528 B, 16B-aligned)
    #pragma unroll
    for (int h = 0; h < 2; ++h) {
        __syncthreads();
        if (wr == h) {
            #pragma unroll
            for (int m = 0; m < 8; m++) {
                int rloc = m * 16 + (lane >> 4) * 4;
                #pragma unroll
                for (int n = 0; n < 4; n++) {
                    int cloc = wc * 64 + n * 16 + lo;
                    #pragma unroll
                    for (int j = 0; j < 4; j++)
                        St[(rloc + j) * 264 + cloc] = f2bf(acc[m][n][j]);
                }
            }
        }
        __syncthreads();
        #pragma unroll
        for (int jj = 0; jj < 8; ++jj) {
            int idx = jj * 512 + tid;         // 0..4095
            int r = idx >> 5, sl = idx & 31;
            uint4 v = *(const uint4*)(St + (size_t)r * 264 + sl * 8);
            *(uint4*)(S2 + (size_t)(rowA + h * 128 + r) * NM + colB + sl * 8) = v;
        }
    }
}

// ---------------- fused: attn-zero + candidate-select + serial fp64 refine ----------------
#define INS(VV) { float x_ = (VV); float h_;                      \
    h_ = fmaxf(t0, x_); x_ = fminf(t0, x_); t0 = h_;              \
    h_ = fmaxf(t1, x_); x_ = fminf(t1, x_); t1 = h_;              \
    h_ = fmaxf(t2, x_); x_ = fminf(t2, x_); t2 = h_;              \
    h_ = fmaxf(t3, x_); x_ = fminf(t3, x_); t3 = h_;              \
    h_ = fmaxf(t4, x_); x_ = fminf(t4, x_); t4 = h_;              \
    h_ = fmaxf(t5, x_); x_ = fminf(t5, x_); t5 = h_;              \
    h_ = fmaxf(t6, x_); x_ = fminf(t6, x_); t6 = h_;              \
    h_ = fmaxf(t7, x_); x_ = fminf(t7, x_); t7 = h_; }

#define ROUND(G) {                                                \
    float mv = t0;                                                \
    mv = fmaxf(mv, __shfl_xor(mv, 1, 64));                        \
    mv = fmaxf(mv, __shfl_xor(mv, 2, 64));                        \
    mv = fmaxf(mv, __shfl_xor(mv, 4, 64));                        \
    mv = fmaxf(mv, __shfl_xor(mv, 8, 64));                        \
    mv = fmaxf(mv, __shfl_xor(mv, 16, 64));                       \
    mv = fmaxf(mv, __shfl_xor(mv, 32, 64));                       \
    G = mv;                                                       \
    bool pop = (t0 == mv);                                        \
    t0 = pop ? t1 : t0; t1 = pop ? t2 : t1; t2 = pop ? t3 : t2;   \
    t3 = pop ? t4 : t3; t4 = pop ? t5 : t4; t5 = pop ? t6 : t5;   \
    t6 = pop ? t7 : t6; t7 = pop ? -__builtin_inff() : t7; }

__global__ __launch_bounds__(256) void candrefine_kernel(const u16* __restrict__ S2,
        const float* __restrict__ x, const float* __restrict__ K,
        const double* __restrict__ invKn,
        float* __restrict__ top8v, u16* __restrict__ top8i,
        float* __restrict__ f_out, float* __restrict__ g_out, float* __restrict__ counts,
        float* __restrict__ attn) {
    __shared__ u16 candl[4][CMAX];
    __shared__ int scnt[4];
    int w    = threadIdx.x >> 6;
    int lane = threadIdx.x & 63;
    int row  = blockIdx.x * 4 + w;
    if (lane == 0) scnt[w] = 0;

    // zero this wave's attn row NOW (fire-and-forget stores; finalize's scatter
    // runs in a LATER kernel, so ordering is guaranteed by the kernel boundary)
    {
        float4 z = {0.f, 0.f, 0.f, 0.f};
        float4* arow = (float4*)(attn + (size_t)row * NM);
        #pragma unroll
        for (int i = 0; i < 8; i++) arow[i * 64 + lane] = z;
    }
    asm volatile("s_waitcnt lgkmcnt(0)" ::: "memory");

    // ---- phase A: candidate selection from bf16 S (wave-local) ----
    {
        const uint4* p = (const uint4*)(S2 + (size_t)row * NM);
        uint4 v[4];
        float t0 = -__builtin_inff(), t1 = t0, t2 = t0, t3 = t0, t4 = t0, t5 = t0, t6 = t0, t7 = t0;
        #pragma unroll
        for (int it = 0; it < 4; ++it) {
            v[it] = p[it * 64 + lane];
            const u32* d = (const u32*)&v[it];
            #pragma unroll
            for (int j = 0; j < 4; ++j) {
                INS(bf2f(d[j] & 0xFFFFu));
                INS(bf2f(d[j] >> 16));
            }
        }
        float g0, g1, g2, g3, g4, g5, g6, g7;
        ROUND(g0); ROUND(g1); ROUND(g2); ROUND(g3);
        ROUND(g4); ROUND(g5); ROUND(g6); ROUND(g7);
        (void)g0; (void)g1; (void)g2; (void)g3; (void)g4; (void)g5; (void)g6;
        float T = g7 - MARGIN;   // dup-pops only lower T -> safe (more candidates)

        #pragma unroll
        for (int it = 0; it < 4; ++it) {
            const u32* d = (const u32*)&v[it];
            #pragma unroll
            for (int j = 0; j < 4; ++j) {
                float flo = bf2f(d[j] & 0xFFFFu);
                float fhi = bf2f(d[j] >> 16);
                int   col = it * 512 + lane * 8 + j * 2;
                if (flo >= T) {
                    int pos = atomicAdd(&scnt[w], 1);
                    if (pos < CMAX) candl[w][pos] = (u16)col;
                }
                if (fhi >= T) {
                    int pos = atomicAdd(&scnt[w], 1);
                    if (pos < CMAX) candl[w][pos] = (u16)(col + 1);
                }
            }
        }
    }
    asm volatile("s_waitcnt lgkmcnt(0)" ::: "memory");

    // ---- phase B: serial fp64 exact rescore (coalesced K loads, TLP-hidden) ----
    const float4* xr = (const float4*)(x + (size_t)row * ND);
    float4 a = xr[lane * 2], b = xr[lane * 2 + 1];
    double x0 = a.x, x1 = a.y, x2 = a.z, x3 = a.w;
    double x4 = b.x, x5 = b.y, x6 = b.z, x7 = b.w;

    double ss = x0*x0 + x1*x1 + x2*x2 + x3*x3 + x4*x4 + x5*x5 + x6*x6 + x7*x7;
    #pragma unroll
    for (int off = 1; off < 64; off <<= 1) ss += __shfl_xor(ss, off, 64);
    double xinv = 1.0 / fmax(sqrt(ss), 1e-12);

    int cnt = min(scnt[w], CMAX);
    int myidx = (lane < cnt) ? (int)candl[w][lane] : 0;
    double myval = -1e300;

    for (int c = 0; c < cnt; ++c) {
        int ci = __shfl(myidx, c, 64);
        const float4* kr = (const float4*)(K + (size_t)ci * ND);
        float4 k0 = kr[lane * 2], k1 = kr[lane * 2 + 1];
        double acc;
        acc = x0 * (double)k0.x;
        acc = fma(x1, (double)k0.y, acc);
        acc = fma(x2, (double)k0.z, acc);
        acc = fma(x3, (double)k0.w, acc);
        acc = fma(x4, (double)k1.x, acc);
        acc = fma(x5, (double)k1.y, acc);
        acc = fma(x6, (double)k1.z, acc);
        acc = fma(x7, (double)k1.w, acc);
        #pragma unroll
        for (int off = 1; off < 64; off <<= 1) acc += __shfl_xor(acc, off, 64);
        double val = acc * xinv * invKn[ci];
        if (lane == c) myval = val;
    }

    float vals[8]; int idxs[8];
    #pragma unroll
    for (int r = 0; r < 8; ++r) {
        double m = myval;
        #pragma unroll
        for (int off = 1; off < 64; off <<= 1) m = fmax(m, __shfl_xor(m, off, 64));
        unsigned long long bal = __ballot(myval == m);
        int wl = __ffsll(bal) - 1;
        int wi = __shfl(myidx, wl, 64);
        vals[r] = (float)m;
        idxs[r] = wi;
        if (lane == wl) myval = -1e300;
    }

    if (lane == 0) {
        float fv = vals[0];
        f_out[row] = fv;
        g_out[row] = 1.0f / (1.0f + expf(FBETA * (fv - FTHETA)));
        atomicAdd(&counts[idxs[0]], 1.0f);
        float4* tv = (float4*)(top8v + (size_t)row * 8);
        tv[0] = (float4){vals[0], vals[1], vals[2], vals[3]};
        tv[1] = (float4){vals[4], vals[5], vals[6], vals[7]};
        uint4 ip;
        ip.x = (u32)idxs[0] | ((u32)idxs[1] << 16);
        ip.y = (u32)idxs[2] | ((u32)idxs[3] << 16);
        ip.z = (u32)idxs[4] | ((u32)idxs[5] << 16);
        ip.w = (u32)idxs[6] | ((u32)idxs[7] << 16);
        *(uint4*)(top8i + (size_t)row * 8) = ip;
    }
}

// ---------------- finalize: softmax(8), scatter into pre-zeroed attn, y = g * attn@V ----------------
__global__ __launch_bounds__(256) void finalize_kernel(const float* __restrict__ top8v,
        const u16* __restrict__ top8i, const float* __restrict__ counts,
        const float* __restrict__ logs, const float* __restrict__ V,
        const float* __restrict__ g_out, float* __restrict__ y, float* __restrict__ attn) {
    int row  = blockIdx.x * 4 + (threadIdx.x >> 6);
    int lane = threadIdx.x & 63;
    float4 z = {0.f, 0.f, 0.f, 0.f};

    float logit = -__builtin_inff();
    int idx = 0;
    if (lane < 8) {
        idx = (int)top8i[(size_t)row * 8 + lane];
        float val = top8v[(size_t)row * 8 + lane];
        logit = val * TAUINV + logs[idx] - (FGAMMA / (float)NB) * counts[idx];
    }
    float mv = logit;
    mv = fmaxf(mv, __shfl_xor(mv, 1, 64));
    mv = fmaxf(mv, __shfl_xor(mv, 2, 64));
    mv = fmaxf(mv, __shfl_xor(mv, 4, 64));
    float e = (lane < 8) ? expf(logit - mv) : 0.0f;
    float sum = e;
    sum += __shfl_xor(sum, 1, 64);
    sum += __shfl_xor(sum, 2, 64);
    sum += __shfl_xor(sum, 4, 64);
    float w = e / sum;   // garbage on lanes >=8, never consumed

    if (lane < 8) attn[(size_t)row * NM + idx] = w;   // row was zeroed by candrefine

    float4 acc0 = z, acc1 = z;
    #pragma unroll
    for (int j = 0; j < 8; j++) {
        float wj = __shfl(w, j, 64);
        int   ij = __shfl(idx, j, 64);
        const float4* vr = (const float4*)(V + (size_t)ij * 512);
        float4 v0 = vr[lane * 2], v1 = vr[lane * 2 + 1];
        acc0.x += wj * v0.x; acc0.y += wj * v0.y; acc0.z += wj * v0.z; acc0.w += wj * v0.w;
        acc1.x += wj * v1.x; acc1.y += wj * v1.y; acc1.z += wj * v1.z; acc1.w += wj * v1.w;
    }
    float gr = g_out[row];
    float4 o0 = {gr * acc0.x, gr * acc0.y, gr * acc0.z, gr * acc0.w};
    float4 o1 = {gr * acc1.x, gr * acc1.y, gr * acc1.z, gr * acc1.w};
    float4* yp = (float4*)(y + (size_t)row * 512);
    yp[lane * 2]     = o0;
    yp[lane * 2 + 1] = o1;
}

extern "C" void kernel_launch(void* const* d_in, const int* in_sizes, int n_in,
                              void* d_out, int out_size, void* d_ws, size_t ws_size,
                              hipStream_t stream) {
    const float* x = (const float*)d_in[0];
    const float* K = (const float*)d_in[1];
    const float* V = (const float*)d_in[2];
    const float* s = (const float*)d_in[3];

    float* y     = (float*)d_out;                       // [32768][512]
    float* f_out = y + (size_t)NB * 512;                // [32768]
    float* g_out = f_out + NB;                          // [32768]
    float* attn  = g_out + NB;                          // [32768][2048]

    char* ws = (char*)d_ws;
    u16*    xn     = (u16*)ws;                          // 33,554,432 B
    u16*    kn     = (u16*)(ws + 33554432);             //  2,097,152 B -> 35,651,584
    float*  logs   = (float*)(ws + 35651584);           //      8,192 B -> 35,659,776
    float*  counts = (float*)(ws + 35659776);           //      8,192 B -> 35,667,968
    double* invKn  = (double*)(ws + 35667968);          //     16,384 B -> 35,684,352
    float*  top8v  = (float*)(ws + 35684352);           //  1,048,576 B -> 36,732,928
    u16*    top8i  = (u16*)(ws + 36732928);             //    524,288 B -> 37,257,216
    u16*    S2     = (u16*)(ws + 67108864);             // 134,217,728 B bf16 scores

    prep_kernel<<<NB / 4 + NM / 4, 256, 0, stream>>>(x, xn, K, kn, invKn, s, logs, counts);
    gemm_kernel<<<1024, 512, 0, stream>>>(xn, kn, S2);
    candrefine_kernel<<<NB / 4, 256, 0, stream>>>(S2, x, K, invKn,
                                                  top8v, top8i, f_out, g_out, counts, attn);
    finalize_kernel<<<NB / 4, 256, 0, stream>>>(top8v, top8i, counts, logs, V,
                                                g_out, y, attn);
}

// Round 9
// 307.269 us; speedup vs baseline: 1.1306x; 1.0160x over previous
//
#include <hip/hip_runtime.h>
#include <math.h>

typedef unsigned short u16;
typedef unsigned int   u32;

#define NB     32768   // batch rows
#define ND     512     // d_in
#define NM     2048    // memory slots
#define TAUINV 10.0f
#define FBETA  10.0f
#define FTHETA 0.5f
#define FGAMMA 0.5f
#define CMAX   32      // candidate cap per row
#define MARGIN 3e-3f   // covers bf16-gemm err + bf16-S rounding

typedef __bf16 bf16x8 __attribute__((ext_vector_type(8)));
typedef float  f32x4  __attribute__((ext_vector_type(4)));

__device__ __forceinline__ u16 f2bf(float x) {
    u32 b = __float_as_uint(x);
    u32 r = (b + 0x7FFFu + ((b >> 16) & 1u)) >> 16;   // RNE
    return (u16)r;
}
__device__ __forceinline__ float bf2f(u32 h) { return __uint_as_float(h << 16); }

// ---------------- merged prep: x rows (f32 norm) + K rows (fp64 norm + side) ----------------
__global__ __launch_bounds__(256) void prep_kernel(const float* __restrict__ x,
        u16* __restrict__ xn, const float* __restrict__ K, u16* __restrict__ kn,
        double* __restrict__ invKn, const float* __restrict__ s,
        float* __restrict__ logs, float* __restrict__ counts) {
    int blk  = blockIdx.x;
    int w    = threadIdx.x >> 6;
    int lane = threadIdx.x & 63;
    if (blk < NB / 4) {                       // ---- x path ----
        int row = blk * 4 + w;
        const float4* p = (const float4*)(x + (size_t)row * ND);
        float4 a = p[lane * 2], b = p[lane * 2 + 1];
        float ss = a.x*a.x + a.y*a.y + a.z*a.z + a.w*a.w +
                   b.x*b.x + b.y*b.y + b.z*b.z + b.w*b.w;
        #pragma unroll
        for (int off = 1; off < 64; off <<= 1) ss += __shfl_xor(ss, off, 64);
        float sc = 1.0f / fmaxf(sqrtf(ss), 1e-12f);
        uint4 o;
        o.x = (u32)f2bf(a.x*sc) | ((u32)f2bf(a.y*sc) << 16);
        o.y = (u32)f2bf(a.z*sc) | ((u32)f2bf(a.w*sc) << 16);
        o.z = (u32)f2bf(b.x*sc) | ((u32)f2bf(b.y*sc) << 16);
        o.w = (u32)f2bf(b.z*sc) | ((u32)f2bf(b.w*sc) << 16);
        ((uint4*)(xn + (size_t)row * ND))[lane] = o;
    } else {                                  // ---- K path ----
        int row = (blk - NB / 4) * 4 + w;
        const float4* p = (const float4*)(K + (size_t)row * ND);
        float4 a = p[lane * 2], b = p[lane * 2 + 1];
        double ss = (double)a.x*a.x + (double)a.y*a.y + (double)a.z*a.z + (double)a.w*a.w +
                    (double)b.x*b.x + (double)b.y*b.y + (double)b.z*b.z + (double)b.w*b.w;
        #pragma unroll
        for (int off = 1; off < 64; off <<= 1) ss += __shfl_xor(ss, off, 64);
        double inv = 1.0 / fmax(sqrt(ss), 1e-12);
        float sc = (float)inv;
        uint4 o;
        o.x = (u32)f2bf(a.x*sc) | ((u32)f2bf(a.y*sc) << 16);
        o.y = (u32)f2bf(a.z*sc) | ((u32)f2bf(a.w*sc) << 16);
        o.z = (u32)f2bf(b.x*sc) | ((u32)f2bf(b.y*sc) << 16);
        o.w = (u32)f2bf(b.z*sc) | ((u32)f2bf(b.w*sc) << 16);
        ((uint4*)(kn + (size_t)row * ND))[lane] = o;
        if (lane == 0) {
            invKn[row]  = inv;
            logs[row]   = logf(s[row] + 1e-8f);
            counts[row] = 0.0f;
        }
    }
}

// ---------------- GEMM: 256x256 tile, 8-wave, 8-phase lockstep, swizzled LDS ----------------
#define GLDS(SRC, OFF) __builtin_amdgcn_global_load_lds( \
    (const __attribute__((address_space(1))) void*)(SRC), \
    (__attribute__((address_space(3))) void*)(smem_c + (OFF)), 16, 0, 0)

#define STAGE8(KTN, D) { \
    _Pragma("unroll") for (int u_ = 0; u_ < 4; ++u_) { \
        _Pragma("unroll") for (int i_ = 0; i_ < 2; ++i_) { \
            int li_ = i_ * 512 + tid; \
            int rl_ = li_ >> 3; \
            int kb_ = ((li_ & 7) * 16) ^ ((rl_ & 7) << 4); \
            const char* src_ = (u_ < 2) \
                ? (const char*)Xn + (((size_t)(rowA + u_ * 128 + rl_)) << 10) + (KTN) * 128 + kb_ \
                : (const char*)Kn + (((size_t)(colB + (u_ - 2) * 128 + rl_)) << 10) + (KTN) * 128 + kb_; \
            GLDS(src_, (u_ < 2 ? 0 : 65536) + (D) * 32768 + (u_ & 1) * 16384 + li_ * 16); \
        } \
    } \
}

#define PHASE(AOFF, BOFF, P) { \
    const int ks_ = (P) >> 1, m4_ = ((P) & 1) * 4; \
    if (((P) & 1) == 0) { \
        _Pragma("unroll") for (int n_ = 0; n_ < 4; ++n_) \
            bq[n_] = *(const bf16x8*)(smem_c + (BOFF) + \
                ((wcl * 64 + n_ * 16 + lo) * 128) + ((ks_ * 64 + hb) ^ swzc)); \
    } \
    _Pragma("unroll") for (int mm_ = 0; mm_ < 4; ++mm_) \
        af[mm_] = *(const bf16x8*)(smem_c + (AOFF) + \
            (((m4_ + mm_) * 16 + lo) * 128) + ((ks_ * 64 + hb) ^ swzc)); \
    __builtin_amdgcn_s_barrier(); \
    __builtin_amdgcn_sched_barrier(0); \
    asm volatile("s_waitcnt lgkmcnt(0)" ::: "memory"); \
    __builtin_amdgcn_sched_barrier(0); \
    __builtin_amdgcn_s_setprio(1); \
    _Pragma("unroll") for (int mm_ = 0; mm_ < 4; ++mm_) \
        _Pragma("unroll") for (int n_ = 0; n_ < 4; ++n_) \
            acc[m4_ + mm_][n_] = __builtin_amdgcn_mfma_f32_16x16x32_bf16( \
                af[mm_], bq[n_], acc[m4_ + mm_][n_], 0, 0, 0); \
    __builtin_amdgcn_s_setprio(0); \
    __builtin_amdgcn_sched_barrier(0); \
    __builtin_amdgcn_s_barrier(); \
    __builtin_amdgcn_sched_barrier(0); \
}

#define TILE(KT, CUR, LASTVM, DOSTAGE) { \
    if (LASTVM) { asm volatile("s_waitcnt vmcnt(0)" ::: "memory"); } \
    else        { asm volatile("s_waitcnt vmcnt(8)" ::: "memory"); } \
    __builtin_amdgcn_s_barrier(); \
    __builtin_amdgcn_sched_barrier(0); \
    bf16x8 af[4], bq[4]; \
    const int aO_ = (CUR) * 32768 + wr * 16384; \
    const int bO_ = 65536 + (CUR) * 32768 + bh * 16384; \
    PHASE(aO_, bO_, 0) \
    PHASE(aO_, bO_, 1) \
    PHASE(aO_, bO_, 2) \
    PHASE(aO_, bO_, 3) \
    if (DOSTAGE) STAGE8((KT) + 2, CUR); \
}

__global__ __launch_bounds__(512, 2) void gemm_kernel(const u16* __restrict__ Xn,
                                                      const u16* __restrict__ Kn,
                                                      u16* __restrict__ S2) {
    __shared__ u16 smem[65536];   // 128 KiB
    char* smem_c = (char*)smem;
    const int tid  = threadIdx.x;
    const int lane = tid & 63;
    const int wid  = tid >> 6;          // 0..7
    const int wr   = wid >> 2;          // 0..1  (M)
    const int wc   = wid & 3;           // 0..3  (N)
    const int wcl  = wc & 1;
    const int bh   = wc >> 1;
    const int lo   = lane & 15;
    const int hb   = (lane >> 4) * 16;  // k-slot byte within 64B k-slice
    const int swzc = (lo & 7) << 4;

    int lin = blockIdx.x;
    int swz = (lin & 7) * 128 + (lin >> 3);
    const int rowA = (swz >> 3) * 256;   // 128 row-panels
    const int colB = (swz & 7) * 256;    // 8 col-panels

    f32x4 acc[8][4];
    #pragma unroll
    for (int m = 0; m < 8; m++)
        #pragma unroll
        for (int n = 0; n < 4; n++) acc[m][n] = (f32x4){0.f, 0.f, 0.f, 0.f};

    STAGE8(0, 0);   // K-tile 0 -> buf0 (8 loads)
    STAGE8(1, 1);   // K-tile 1 -> buf1 (8 loads)

    for (int kt2 = 0; kt2 < 6; kt2 += 2) {
        TILE(kt2,     0, 0, 1)
        TILE(kt2 + 1, 1, 0, 1)
    }
    TILE(6, 0, 0, 0)
    TILE(7, 1, 1, 0)

    // epilogue: repack 256x256 fp32 acc -> bf16 via LDS, two 128-row passes
    u16* St = smem;                      // [128][264] u16 (row stride 528 B, 16B-aligned)
    #pragma unroll
    for (int h = 0; h < 2; ++h) {
        __syncthreads();
        if (wr == h) {
            #pragma unroll
            for (int m = 0; m < 8; m++) {
                int rloc = m * 16 + (lane >> 4) * 4;
                #pragma unroll
                for (int n = 0; n < 4; n++) {
                    int cloc = wc * 64 + n * 16 + lo;
                    #pragma unroll
                    for (int j = 0; j < 4; j++)
                        St[(rloc + j) * 264 + cloc] = f2bf(acc[m][n][j]);
                }
            }
        }
        __syncthreads();
        #pragma unroll
        for (int jj = 0; jj < 8; ++jj) {
            int idx = jj * 512 + tid;         // 0..4095
            int r = idx >> 5, sl = idx & 31;
            uint4 v = *(const uint4*)(St + (size_t)r * 264 + sl * 8);
            *(uint4*)(S2 + (size_t)(rowA + h * 128 + r) * NM + colB + sl * 8) = v;
        }
    }
}

// ---------------- fused: attn-zero + candidate-select + serial fp64 refine ----------------
#define INS(VV) { float x_ = (VV); float h_;                      \
    h_ = fmaxf(t0, x_); x_ = fminf(t0, x_); t0 = h_;              \
    h_ = fmaxf(t1, x_); x_ = fminf(t1, x_); t1 = h_;              \
    h_ = fmaxf(t2, x_); x_ = fminf(t2, x_); t2 = h_;              \
    h_ = fmaxf(t3, x_); x_ = fminf(t3, x_); t3 = h_;              \
    h_ = fmaxf(t4, x_); x_ = fminf(t4, x_); t4 = h_;              \
    h_ = fmaxf(t5, x_); x_ = fminf(t5, x_); t5 = h_;              \
    h_ = fmaxf(t6, x_); x_ = fminf(t6, x_); t6 = h_;              \
    h_ = fmaxf(t7, x_); x_ = fminf(t7, x_); t7 = h_; }

#define ROUND(G) {                                                \
    float mv = t0;                                                \
    mv = fmaxf(mv, __shfl_xor(mv, 1, 64));                        \
    mv = fmaxf(mv, __shfl_xor(mv, 2, 64));                        \
    mv = fmaxf(mv, __shfl_xor(mv, 4, 64));                        \
    mv = fmaxf(mv, __shfl_xor(mv, 8, 64));                        \
    mv = fmaxf(mv, __shfl_xor(mv, 16, 64));                       \
    mv = fmaxf(mv, __shfl_xor(mv, 32, 64));                       \
    G = mv;                                                       \
    bool pop = (t0 == mv);                                        \
    t0 = pop ? t1 : t0; t1 = pop ? t2 : t1; t2 = pop ? t3 : t2;   \
    t3 = pop ? t4 : t3; t4 = pop ? t5 : t4; t5 = pop ? t6 : t5;   \
    t6 = pop ? t7 : t6; t7 = pop ? -__builtin_inff() : t7; }

__global__ __launch_bounds__(256) void candrefine_kernel(const u16* __restrict__ S2,
        const float* __restrict__ x, const float* __restrict__ K,
        const double* __restrict__ invKn,
        float* __restrict__ top8v, u16* __restrict__ top8i,
        float* __restrict__ f_out, float* __restrict__ g_out, float* __restrict__ counts,
        float* __restrict__ attn) {
    __shared__ u16 candl[4][CMAX];
    __shared__ int scnt[4];
    int w    = threadIdx.x >> 6;
    int lane = threadIdx.x & 63;
    int row  = blockIdx.x * 4 + w;
    if (lane == 0) scnt[w] = 0;

    // zero this wave's attn row NOW (fire-and-forget stores; finalize's scatter
    // runs in a LATER kernel, so ordering is guaranteed by the kernel boundary)
    {
        float4 z = {0.f, 0.f, 0.f, 0.f};
        float4* arow = (float4*)(attn + (size_t)row * NM);
        #pragma unroll
        for (int i = 0; i < 8; i++) arow[i * 64 + lane] = z;
    }
    asm volatile("s_waitcnt lgkmcnt(0)" ::: "memory");

    // ---- phase A: candidate selection from bf16 S (wave-local) ----
    {
        const uint4* p = (const uint4*)(S2 + (size_t)row * NM);
        uint4 v[4];
        float t0 = -__builtin_inff(), t1 = t0, t2 = t0, t3 = t0, t4 = t0, t5 = t0, t6 = t0, t7 = t0;
        #pragma unroll
        for (int it = 0; it < 4; ++it) {
            v[it] = p[it * 64 + lane];
            const u32* d = (const u32*)&v[it];
            #pragma unroll
            for (int j = 0; j < 4; ++j) {
                INS(bf2f(d[j] & 0xFFFFu));
                INS(bf2f(d[j] >> 16));
            }
        }
        float g0, g1, g2, g3, g4, g5, g6, g7;
        ROUND(g0); ROUND(g1); ROUND(g2); ROUND(g3);
        ROUND(g4); ROUND(g5); ROUND(g6); ROUND(g7);
        (void)g0; (void)g1; (void)g2; (void)g3; (void)g4; (void)g5; (void)g6;
        float T = g7 - MARGIN;   // dup-pops only lower T -> safe (more candidates)

        #pragma unroll
        for (int it = 0; it < 4; ++it) {
            const u32* d = (const u32*)&v[it];
            #pragma unroll
            for (int j = 0; j < 4; ++j) {
                float flo = bf2f(d[j] & 0xFFFFu);
                float fhi = bf2f(d[j] >> 16);
                int   col = it * 512 + lane * 8 + j * 2;
                if (flo >= T) {
                    int pos = atomicAdd(&scnt[w], 1);
                    if (pos < CMAX) candl[w][pos] = (u16)col;
                }
                if (fhi >= T) {
                    int pos = atomicAdd(&scnt[w], 1);
                    if (pos < CMAX) candl[w][pos] = (u16)(col + 1);
                }
            }
        }
    }
    asm volatile("s_waitcnt lgkmcnt(0)" ::: "memory");

    // ---- phase B: serial fp64 exact rescore (coalesced K loads, TLP-hidden) ----
    const float4* xr = (const float4*)(x + (size_t)row * ND);
    float4 a = xr[lane * 2], b = xr[lane * 2 + 1];
    double x0 = a.x, x1 = a.y, x2 = a.z, x3 = a.w;
    double x4 = b.x, x5 = b.y, x6 = b.z, x7 = b.w;

    double ss = x0*x0 + x1*x1 + x2*x2 + x3*x3 + x4*x4 + x5*x5 + x6*x6 + x7*x7;
    #pragma unroll
    for (int off = 1; off < 64; off <<= 1) ss += __shfl_xor(ss, off, 64);
    double xinv = 1.0 / fmax(sqrt(ss), 1e-12);

    int cnt = min(scnt[w], CMAX);        // >= 8 always (top-8 themselves pass T)
    int myidx = (lane < cnt) ? (int)candl[w][lane] : 0;
    double myval = -1e300;

    for (int c = 0; c < cnt; ++c) {
        int ci = __shfl(myidx, c, 64);
        const float4* kr = (const float4*)(K + (size_t)ci * ND);
        float4 k0 = kr[lane * 2], k1 = kr[lane * 2 + 1];
        double acc;
        acc = x0 * (double)k0.x;
        acc = fma(x1, (double)k0.y, acc);
        acc = fma(x2, (double)k0.z, acc);
        acc = fma(x3, (double)k0.w, acc);
        acc = fma(x4, (double)k1.x, acc);
        acc = fma(x5, (double)k1.y, acc);
        acc = fma(x6, (double)k1.z, acc);
        acc = fma(x7, (double)k1.w, acc);
        #pragma unroll
        for (int off = 1; off < 64; off <<= 1) acc += __shfl_xor(acc, off, 64);
        double val = acc * xinv * invKn[ci];
        if (lane == c) myval = val;
    }

    // ---- rank-based exact top-8 (replaces 8 serial fp64 wave-max rounds) ----
    // Total order: (value desc, idx asc). Valid lanes have unique idx -> unique
    // ranks 0..cnt-1. Invalid lanes (myval=-1e300, myidx=0) tie each other
    // (not counted as better) and are beaten by all valid lanes -> rank >= cnt >= 8.
    int rank = 0;
    for (int c = 0; c < cnt; ++c) {
        double bv = __shfl(myval, c, 64);
        int    bi = __shfl(myidx, c, 64);
        if (bv > myval || (bv == myval && bi < myidx)) rank++;
    }
    if (lane < cnt && rank < 8) {
        top8v[(size_t)row * 8 + rank] = (float)myval;
        top8i[(size_t)row * 8 + rank] = (u16)myidx;
        if (rank == 0) {
            float fv = (float)myval;
            f_out[row] = fv;
            g_out[row] = 1.0f / (1.0f + expf(FBETA * (fv - FTHETA)));
            atomicAdd(&counts[myidx], 1.0f);
        }
    }
}

// ---------------- finalize: softmax(8), scatter into pre-zeroed attn, y = g * attn@V ----------------
__global__ __launch_bounds__(256) void finalize_kernel(const float* __restrict__ top8v,
        const u16* __restrict__ top8i, const float* __restrict__ counts,
        const float* __restrict__ logs, const float* __restrict__ V,
        const float* __restrict__ g_out, float* __restrict__ y, float* __restrict__ attn) {
    int row  = blockIdx.x * 4 + (threadIdx.x >> 6);
    int lane = threadIdx.x & 63;
    float4 z = {0.f, 0.f, 0.f, 0.f};

    float logit = -__builtin_inff();
    int idx = 0;
    if (lane < 8) {
        idx = (int)top8i[(size_t)row * 8 + lane];
        float val = top8v[(size_t)row * 8 + lane];
        logit = val * TAUINV + logs[idx] - (FGAMMA / (float)NB) * counts[idx];
    }
    float mv = logit;
    mv = fmaxf(mv, __shfl_xor(mv, 1, 64));
    mv = fmaxf(mv, __shfl_xor(mv, 2, 64));
    mv = fmaxf(mv, __shfl_xor(mv, 4, 64));
    float e = (lane < 8) ? expf(logit - mv) : 0.0f;
    float sum = e;
    sum += __shfl_xor(sum, 1, 64);
    sum += __shfl_xor(sum, 2, 64);
    sum += __shfl_xor(sum, 4, 64);
    float w = e / sum;   // garbage on lanes >=8, never consumed

    if (lane < 8) attn[(size_t)row * NM + idx] = w;   // row was zeroed by candrefine

    float4 acc0 = z, acc1 = z;
    #pragma unroll
    for (int j = 0; j < 8; j++) {
        float wj = __shfl(w, j, 64);
        int   ij = __shfl(idx, j, 64);
        const float4* vr = (const float4*)(V + (size_t)ij * 512);
        float4 v0 = vr[lane * 2], v1 = vr[lane * 2 + 1];
        acc0.x += wj * v0.x; acc0.y += wj * v0.y; acc0.z += wj * v0.z; acc0.w += wj * v0.w;
        acc1.x += wj * v1.x; acc1.y += wj * v1.y; acc1.z += wj * v1.z; acc1.w += wj * v1.w;
    }
    float gr = g_out[row];
    float4 o0 = {gr * acc0.x, gr * acc0.y, gr * acc0.z, gr * acc0.w};
    float4 o1 = {gr * acc1.x, gr * acc1.y, gr * acc1.z, gr * acc1.w};
    float4* yp = (float4*)(y + (size_t)row * 512);
    yp[lane * 2]     = o0;
    yp[lane * 2 + 1] = o1;
}

extern "C" void kernel_launch(void* const* d_in, const int* in_sizes, int n_in,
                              void* d_out, int out_size, void* d_ws, size_t ws_size,
                              hipStream_t stream) {
    const float* x = (const float*)d_in[0];
    const float* K = (const float*)d_in[1];
    const float* V = (const float*)d_in[2];
    const float* s = (const float*)d_in[3];

    float* y     = (float*)d_out;                       // [32768][512]
    float* f_out = y + (size_t)NB * 512;                // [32768]
    float* g_out = f_out + NB;                          // [32768]
    float* attn  = g_out + NB;                          // [32768][2048]

    char* ws = (char*)d_ws;
    u16*    xn     = (u16*)ws;                          // 33,554,432 B
    u16*    kn     = (u16*)(ws + 33554432);             //  2,097,152 B -> 35,651,584
    float*  logs   = (float*)(ws + 35651584);           //      8,192 B -> 35,659,776
    float*  counts = (float*)(ws + 35659776);           //      8,192 B -> 35,667,968
    double* invKn  = (double*)(ws + 35667968);          //     16,384 B -> 35,684,352
    float*  top8v  = (float*)(ws + 35684352);           //  1,048,576 B -> 36,732,928
    u16*    top8i  = (u16*)(ws + 36732928);             //    524,288 B -> 37,257,216
    u16*    S2     = (u16*)(ws + 67108864);             // 134,217,728 B bf16 scores

    prep_kernel<<<NB / 4 + NM / 4, 256, 0, stream>>>(x, xn, K, kn, invKn, s, logs, counts);
    gemm_kernel<<<1024, 512, 0, stream>>>(xn, kn, S2);
    candrefine_kernel<<<NB / 4, 256, 0, stream>>>(S2, x, K, invKn,
                                                  top8v, top8i, f_out, g_out, counts, attn);
    finalize_kernel<<<NB / 4, 256, 0, stream>>>(top8v, top8i, counts, logs, V,
                                                g_out, y, attn);
}

// Round 11
// 260.367 us; speedup vs baseline: 1.3342x; 1.1801x over previous
//
#include <hip/hip_runtime.h>
#include <math.h>

typedef unsigned short u16;
typedef unsigned int   u32;

#define NB     32768   // batch rows
#define ND     512     // d_in
#define NM     2048    // memory slots
#define TAUINV 10.0f
#define FBETA  10.0f
#define FTHETA 0.5f
#define FGAMMA 0.5f
#define CMAX   32      // candidate cap per row
#define MARGIN 3e-3f   // covers bf16-gemm err + bf16-S rounding

typedef __bf16 bf16x8 __attribute__((ext_vector_type(8)));
typedef float  f32x4  __attribute__((ext_vector_type(4)));

__device__ __forceinline__ u16 f2bf(float x) {
    u32 b = __float_as_uint(x);
    u32 r = (b + 0x7FFFu + ((b >> 16) & 1u)) >> 16;   // RNE
    return (u16)r;
}
__device__ __forceinline__ float bf2f(u32 h) { return __uint_as_float(h << 16); }

// ---------------- merged prep: x rows (f32 norm) + K rows (fp64 norm + side) ----------------
__global__ __launch_bounds__(256) void prep_kernel(const float* __restrict__ x,
        u16* __restrict__ xn, const float* __restrict__ K, u16* __restrict__ kn,
        double* __restrict__ invKn, const float* __restrict__ s,
        float* __restrict__ logs, float* __restrict__ counts) {
    int blk  = blockIdx.x;
    int w    = threadIdx.x >> 6;
    int lane = threadIdx.x & 63;
    if (blk < NB / 4) {                       // ---- x path ----
        int row = blk * 4 + w;
        const float4* p = (const float4*)(x + (size_t)row * ND);
        float4 a = p[lane * 2], b = p[lane * 2 + 1];
        float ss = a.x*a.x + a.y*a.y + a.z*a.z + a.w*a.w +
                   b.x*b.x + b.y*b.y + b.z*b.z + b.w*b.w;
        #pragma unroll
        for (int off = 1; off < 64; off <<= 1) ss += __shfl_xor(ss, off, 64);
        float sc = 1.0f / fmaxf(sqrtf(ss), 1e-12f);
        uint4 o;
        o.x = (u32)f2bf(a.x*sc) | ((u32)f2bf(a.y*sc) << 16);
        o.y = (u32)f2bf(a.z*sc) | ((u32)f2bf(a.w*sc) << 16);
        o.z = (u32)f2bf(b.x*sc) | ((u32)f2bf(b.y*sc) << 16);
        o.w = (u32)f2bf(b.z*sc) | ((u32)f2bf(b.w*sc) << 16);
        ((uint4*)(xn + (size_t)row * ND))[lane] = o;
    } else {                                  // ---- K path ----
        int row = (blk - NB / 4) * 4 + w;
        const float4* p = (const float4*)(K + (size_t)row * ND);
        float4 a = p[lane * 2], b = p[lane * 2 + 1];
        double ss = (double)a.x*a.x + (double)a.y*a.y + (double)a.z*a.z + (double)a.w*a.w +
                    (double)b.x*b.x + (double)b.y*b.y + (double)b.z*b.z + (double)b.w*b.w;
        #pragma unroll
        for (int off = 1; off < 64; off <<= 1) ss += __shfl_xor(ss, off, 64);
        double inv = 1.0 / fmax(sqrt(ss), 1e-12);
        float sc = (float)inv;
        uint4 o;
        o.x = (u32)f2bf(a.x*sc) | ((u32)f2bf(a.y*sc) << 16);
        o.y = (u32)f2bf(a.z*sc) | ((u32)f2bf(a.w*sc) << 16);
        o.z = (u32)f2bf(b.x*sc) | ((u32)f2bf(b.y*sc) << 16);
        o.w = (u32)f2bf(b.z*sc) | ((u32)f2bf(b.w*sc) << 16);
        ((uint4*)(kn + (size_t)row * ND))[lane] = o;
        if (lane == 0) {
            invKn[row]  = inv;
            logs[row]   = logf(s[row] + 1e-8f);
            counts[row] = 0.0f;
        }
    }
}

// ---------------- GEMM: 256x256 tile, 8-wave, 8-phase lockstep, swizzled LDS ----------------
#define GLDS(SRC, OFF) __builtin_amdgcn_global_load_lds( \
    (const __attribute__((address_space(1))) void*)(SRC), \
    (__attribute__((address_space(3))) void*)(smem_c + (OFF)), 16, 0, 0)

#define STAGE8(KTN, D) { \
    _Pragma("unroll") for (int u_ = 0; u_ < 4; ++u_) { \
        _Pragma("unroll") for (int i_ = 0; i_ < 2; ++i_) { \
            int li_ = i_ * 512 + tid; \
            int rl_ = li_ >> 3; \
            int kb_ = ((li_ & 7) * 16) ^ ((rl_ & 7) << 4); \
            const char* src_ = (u_ < 2) \
                ? (const char*)Xn + (((size_t)(rowA + u_ * 128 + rl_)) << 10) + (KTN) * 128 + kb_ \
                : (const char*)Kn + (((size_t)(colB + (u_ - 2) * 128 + rl_)) << 10) + (KTN) * 128 + kb_; \
            GLDS(src_, (u_ < 2 ? 0 : 65536) + (D) * 32768 + (u_ & 1) * 16384 + li_ * 16); \
        } \
    } \
}

#define PHASE(AOFF, BOFF, P) { \
    const int ks_ = (P) >> 1, m4_ = ((P) & 1) * 4; \
    if (((P) & 1) == 0) { \
        _Pragma("unroll") for (int n_ = 0; n_ < 4; ++n_) \
            bq[n_] = *(const bf16x8*)(smem_c + (BOFF) + \
                ((wcl * 64 + n_ * 16 + lo) * 128) + ((ks_ * 64 + hb) ^ swzc)); \
    } \
    _Pragma("unroll") for (int mm_ = 0; mm_ < 4; ++mm_) \
        af[mm_] = *(const bf16x8*)(smem_c + (AOFF) + \
            (((m4_ + mm_) * 16 + lo) * 128) + ((ks_ * 64 + hb) ^ swzc)); \
    __builtin_amdgcn_s_barrier(); \
    __builtin_amdgcn_sched_barrier(0); \
    asm volatile("s_waitcnt lgkmcnt(0)" ::: "memory"); \
    __builtin_amdgcn_sched_barrier(0); \
    __builtin_amdgcn_s_setprio(1); \
    _Pragma("unroll") for (int mm_ = 0; mm_ < 4; ++mm_) \
        _Pragma("unroll") for (int n_ = 0; n_ < 4; ++n_) \
            acc[m4_ + mm_][n_] = __builtin_amdgcn_mfma_f32_16x16x32_bf16( \
                af[mm_], bq[n_], acc[m4_ + mm_][n_], 0, 0, 0); \
    __builtin_amdgcn_s_setprio(0); \
    __builtin_amdgcn_sched_barrier(0); \
    __builtin_amdgcn_s_barrier(); \
    __builtin_amdgcn_sched_barrier(0); \
}

#define TILE(KT, CUR, LASTVM, DOSTAGE) { \
    if (LASTVM) { asm volatile("s_waitcnt vmcnt(0)" ::: "memory"); } \
    else        { asm volatile("s_waitcnt vmcnt(8)" ::: "memory"); } \
    __builtin_amdgcn_s_barrier(); \
    __builtin_amdgcn_sched_barrier(0); \
    bf16x8 af[4], bq[4]; \
    const int aO_ = (CUR) * 32768 + wr * 16384; \
    const int bO_ = 65536 + (CUR) * 32768 + bh * 16384; \
    PHASE(aO_, bO_, 0) \
    PHASE(aO_, bO_, 1) \
    PHASE(aO_, bO_, 2) \
    PHASE(aO_, bO_, 3) \
    if (DOSTAGE) STAGE8((KT) + 2, CUR); \
}

__global__ __launch_bounds__(512, 2) void gemm_kernel(const u16* __restrict__ Xn,
                                                      const u16* __restrict__ Kn,
                                                      u16* __restrict__ S2) {
    __shared__ u16 smem[65536];   // 128 KiB
    char* smem_c = (char*)smem;
    const int tid  = threadIdx.x;
    const int lane = tid & 63;
    const int wid  = tid >> 6;          // 0..7
    const int wr   = wid >> 2;          // 0..1  (M)
    const int wc   = wid & 3;           // 0..3  (N)
    const int wcl  = wc & 1;
    const int bh   = wc >> 1;
    const int lo   = lane & 15;
    const int hb   = (lane >> 4) * 16;  // k-slot byte within 64B k-slice
    const int swzc = (lo & 7) << 4;

    int lin = blockIdx.x;
    int swz = (lin & 7) * 128 + (lin >> 3);
    const int rowA = (swz >> 3) * 256;   // 128 row-panels
    const int colB = (swz & 7) * 256;    // 8 col-panels

    f32x4 acc[8][4];
    #pragma unroll
    for (int m = 0; m < 8; m++)
        #pragma unroll
        for (int n = 0; n < 4; n++) acc[m][n] = (f32x4){0.f, 0.f, 0.f, 0.f};

    STAGE8(0, 0);   // K-tile 0 -> buf0 (8 loads)
    STAGE8(1, 1);   // K-tile 1 -> buf1 (8 loads)

    for (int kt2 = 0; kt2 < 6; kt2 += 2) {
        TILE(kt2,     0, 0, 1)
        TILE(kt2 + 1, 1, 0, 1)
    }
    TILE(6, 0, 0, 0)
    TILE(7, 1, 1, 0)

    // epilogue: repack 256x256 fp32 acc -> bf16 via LDS, two 128-row passes
    u16* St = smem;                      // [128][264] u16 (row stride 528 B, 16B-aligned)
    #pragma unroll
    for (int h = 0; h < 2; ++h) {
        __syncthreads();
        if (wr == h) {
            #pragma unroll
            for (int m = 0; m < 8; m++) {
                int rloc = m * 16 + (lane >> 4) * 4;
                #pragma unroll
                for (int n = 0; n < 4; n++) {
                    int cloc = wc * 64 + n * 16 + lo;
                    #pragma unroll
                    for (int j = 0; j < 4; j++)
                        St[(rloc + j) * 264 + cloc] = f2bf(acc[m][n][j]);
                }
            }
        }
        __syncthreads();
        #pragma unroll
        for (int jj = 0; jj < 8; ++jj) {
            int idx = jj * 512 + tid;         // 0..4095
            int r = idx >> 5, sl = idx & 31;
            uint4 v = *(const uint4*)(St + (size_t)r * 264 + sl * 8);
            *(uint4*)(S2 + (size_t)(rowA + h * 128 + r) * NM + colB + sl * 8) = v;
        }
    }
}

// ---------------- fused: attn-zero (non-temporal) + candidate-select + fp64 refine ----------------
#define INS(VV) { float x_ = (VV); float h_;                      \
    h_ = fmaxf(t0, x_); x_ = fminf(t0, x_); t0 = h_;              \
    h_ = fmaxf(t1, x_); x_ = fminf(t1, x_); t1 = h_;              \
    h_ = fmaxf(t2, x_); x_ = fminf(t2, x_); t2 = h_;              \
    h_ = fmaxf(t3, x_); x_ = fminf(t3, x_); t3 = h_;              \
    h_ = fmaxf(t4, x_); x_ = fminf(t4, x_); t4 = h_;              \
    h_ = fmaxf(t5, x_); x_ = fminf(t5, x_); t5 = h_;              \
    h_ = fmaxf(t6, x_); x_ = fminf(t6, x_); t6 = h_;              \
    h_ = fmaxf(t7, x_); x_ = fminf(t7, x_); t7 = h_; }

#define ROUND(G) {                                                \
    float mv = t0;                                                \
    mv = fmaxf(mv, __shfl_xor(mv, 1, 64));                        \
    mv = fmaxf(mv, __shfl_xor(mv, 2, 64));                        \
    mv = fmaxf(mv, __shfl_xor(mv, 4, 64));                        \
    mv = fmaxf(mv, __shfl_xor(mv, 8, 64));                        \
    mv = fmaxf(mv, __shfl_xor(mv, 16, 64));                       \
    mv = fmaxf(mv, __shfl_xor(mv, 32, 64));                       \
    G = mv;                                                       \
    bool pop = (t0 == mv);                                        \
    t0 = pop ? t1 : t0; t1 = pop ? t2 : t1; t2 = pop ? t3 : t2;   \
    t3 = pop ? t4 : t3; t4 = pop ? t5 : t4; t5 = pop ? t6 : t5;   \
    t6 = pop ? t7 : t6; t7 = pop ? -__builtin_inff() : t7; }

__global__ __launch_bounds__(256) void candrefine_kernel(const u16* __restrict__ S2,
        const float* __restrict__ x, const float* __restrict__ K,
        const double* __restrict__ invKn,
        float* __restrict__ top8v, u16* __restrict__ top8i,
        float* __restrict__ f_out, float* __restrict__ g_out, float* __restrict__ counts,
        float* __restrict__ attn) {
    __shared__ u16 candl[4][CMAX];
    __shared__ int scnt[4];
    int w    = threadIdx.x >> 6;
    int lane = threadIdx.x & 63;
    int row  = blockIdx.x * 4 + w;
    if (lane == 0) scnt[w] = 0;

    // zero this wave's attn row NOW with NON-TEMPORAL stores (ext-vector type for
    // the builtin): the 268 MB zero stream must not evict the L3-resident S2
    // (134 MB) this same kernel reads. Visibility for finalize: kernel boundary.
    {
        f32x4 z = {0.f, 0.f, 0.f, 0.f};
        f32x4* arow = (f32x4*)(attn + (size_t)row * NM);
        #pragma unroll
        for (int i = 0; i < 8; i++)
            __builtin_nontemporal_store(z, &arow[i * 64 + lane]);
    }
    asm volatile("s_waitcnt lgkmcnt(0)" ::: "memory");

    // ---- phase A: candidate selection from bf16 S (wave-local) ----
    {
        const uint4* p = (const uint4*)(S2 + (size_t)row * NM);
        uint4 v[4];
        float t0 = -__builtin_inff(), t1 = t0, t2 = t0, t3 = t0, t4 = t0, t5 = t0, t6 = t0, t7 = t0;
        #pragma unroll
        for (int it = 0; it < 4; ++it) {
            v[it] = p[it * 64 + lane];
            const u32* d = (const u32*)&v[it];
            #pragma unroll
            for (int j = 0; j < 4; ++j) {
                INS(bf2f(d[j] & 0xFFFFu));
                INS(bf2f(d[j] >> 16));
            }
        }
        float g0, g1, g2, g3, g4, g5, g6, g7;
        ROUND(g0); ROUND(g1); ROUND(g2); ROUND(g3);
        ROUND(g4); ROUND(g5); ROUND(g6); ROUND(g7);
        (void)g0; (void)g1; (void)g2; (void)g3; (void)g4; (void)g5; (void)g6;
        float T = g7 - MARGIN;   // dup-pops only lower T -> safe (more candidates)

        #pragma unroll
        for (int it = 0; it < 4; ++it) {
            const u32* d = (const u32*)&v[it];
            #pragma unroll
            for (int j = 0; j < 4; ++j) {
                float flo = bf2f(d[j] & 0xFFFFu);
                float fhi = bf2f(d[j] >> 16);
                int   col = it * 512 + lane * 8 + j * 2;
                if (flo >= T) {
                    int pos = atomicAdd(&scnt[w], 1);
                    if (pos < CMAX) candl[w][pos] = (u16)col;
                }
                if (fhi >= T) {
                    int pos = atomicAdd(&scnt[w], 1);
                    if (pos < CMAX) candl[w][pos] = (u16)(col + 1);
                }
            }
        }
    }
    asm volatile("s_waitcnt lgkmcnt(0)" ::: "memory");

    // ---- phase B: serial fp64 exact rescore (coalesced K loads, TLP-hidden) ----
    const float4* xr = (const float4*)(x + (size_t)row * ND);
    float4 a = xr[lane * 2], b = xr[lane * 2 + 1];
    double x0 = a.x, x1 = a.y, x2 = a.z, x3 = a.w;
    double x4 = b.x, x5 = b.y, x6 = b.z, x7 = b.w;

    double ss = x0*x0 + x1*x1 + x2*x2 + x3*x3 + x4*x4 + x5*x5 + x6*x6 + x7*x7;
    #pragma unroll
    for (int off = 1; off < 64; off <<= 1) ss += __shfl_xor(ss, off, 64);
    double xinv = 1.0 / fmax(sqrt(ss), 1e-12);

    int cnt = min(scnt[w], CMAX);        // >= 8 always (top-8 themselves pass T)
    int myidx = (lane < cnt) ? (int)candl[w][lane] : 0;
    double myval = -1e300;

    for (int c = 0; c < cnt; ++c) {
        int ci = __shfl(myidx, c, 64);
        const float4* kr = (const float4*)(K + (size_t)ci * ND);
        float4 k0 = kr[lane * 2], k1 = kr[lane * 2 + 1];
        double acc;
        acc = x0 * (double)k0.x;
        acc = fma(x1, (double)k0.y, acc);
        acc = fma(x2, (double)k0.z, acc);
        acc = fma(x3, (double)k0.w, acc);
        acc = fma(x4, (double)k1.x, acc);
        acc = fma(x5, (double)k1.y, acc);
        acc = fma(x6, (double)k1.z, acc);
        acc = fma(x7, (double)k1.w, acc);
        #pragma unroll
        for (int off = 1; off < 64; off <<= 1) acc += __shfl_xor(acc, off, 64);
        double val = acc * xinv * invKn[ci];
        if (lane == c) myval = val;
    }

    // ---- rank-based exact top-8 ----
    int rank = 0;
    for (int c = 0; c < cnt; ++c) {
        double bv = __shfl(myval, c, 64);
        int    bi = __shfl(myidx, c, 64);
        if (bv > myval || (bv == myval && bi < myidx)) rank++;
    }
    if (lane < cnt && rank < 8) {
        top8v[(size_t)row * 8 + rank] = (float)myval;
        top8i[(size_t)row * 8 + rank] = (u16)myidx;
        if (rank == 0) {
            float fv = (float)myval;
            f_out[row] = fv;
            g_out[row] = 1.0f / (1.0f + expf(FBETA * (fv - FTHETA)));
            atomicAdd(&counts[myidx], 1.0f);
        }
    }
}

// ---------------- finalize: softmax(8), scatter into pre-zeroed attn, y = g * attn@V ----------------
__global__ __launch_bounds__(256) void finalize_kernel(const float* __restrict__ top8v,
        const u16* __restrict__ top8i, const float* __restrict__ counts,
        const float* __restrict__ logs, const float* __restrict__ V,
        const float* __restrict__ g_out, float* __restrict__ y, float* __restrict__ attn) {
    int row  = blockIdx.x * 4 + (threadIdx.x >> 6);
    int lane = threadIdx.x & 63;
    float4 z = {0.f, 0.f, 0.f, 0.f};

    float logit = -__builtin_inff();
    int idx = 0;
    if (lane < 8) {
        idx = (int)top8i[(size_t)row * 8 + lane];
        float val = top8v[(size_t)row * 8 + lane];
        logit = val * TAUINV + logs[idx] - (FGAMMA / (float)NB) * counts[idx];
    }
    float mv = logit;
    mv = fmaxf(mv, __shfl_xor(mv, 1, 64));
    mv = fmaxf(mv, __shfl_xor(mv, 2, 64));
    mv = fmaxf(mv, __shfl_xor(mv, 4, 64));
    float e = (lane < 8) ? expf(logit - mv) : 0.0f;
    float sum = e;
    sum += __shfl_xor(sum, 1, 64);
    sum += __shfl_xor(sum, 2, 64);
    sum += __shfl_xor(sum, 4, 64);
    float w = e / sum;   // garbage on lanes >=8, never consumed

    if (lane < 8) attn[(size_t)row * NM + idx] = w;   // row was zeroed by candrefine

    float4 acc0 = z, acc1 = z;
    #pragma unroll
    for (int j = 0; j < 8; j++) {
        float wj = __shfl(w, j, 64);
        int   ij = __shfl(idx, j, 64);
        const float4* vr = (const float4*)(V + (size_t)ij * 512);
        float4 v0 = vr[lane * 2], v1 = vr[lane * 2 + 1];
        acc0.x += wj * v0.x; acc0.y += wj * v0.y; acc0.z += wj * v0.z; acc0.w += wj * v0.w;
        acc1.x += wj * v1.x; acc1.y += wj * v1.y; acc1.z += wj * v1.z; acc1.w += wj * v1.w;
    }
    float gr = g_out[row];
    f32x4 o0 = {gr * acc0.x, gr * acc0.y, gr * acc0.z, gr * acc0.w};
    f32x4 o1 = {gr * acc1.x, gr * acc1.y, gr * acc1.z, gr * acc1.w};
    f32x4* yp = (f32x4*)(y + (size_t)row * 512);
    __builtin_nontemporal_store(o0, &yp[lane * 2]);      // y never re-read on device
    __builtin_nontemporal_store(o1, &yp[lane * 2 + 1]);
}

extern "C" void kernel_launch(void* const* d_in, const int* in_sizes, int n_in,
                              void* d_out, int out_size, void* d_ws, size_t ws_size,
                              hipStream_t stream) {
    const float* x = (const float*)d_in[0];
    const float* K = (const float*)d_in[1];
    const float* V = (const float*)d_in[2];
    const float* s = (const float*)d_in[3];

    float* y     = (float*)d_out;                       // [32768][512]
    float* f_out = y + (size_t)NB * 512;                // [32768]
    float* g_out = f_out + NB;                          // [32768]
    float* attn  = g_out + NB;                          // [32768][2048]

    char* ws = (char*)d_ws;
    u16*    xn     = (u16*)ws;                          // 33,554,432 B
    u16*    kn     = (u16*)(ws + 33554432);             //  2,097,152 B -> 35,651,584
    float*  logs   = (float*)(ws + 35651584);           //      8,192 B -> 35,659,776
    float*  counts = (float*)(ws + 35659776);           //      8,192 B -> 35,667,968
    double* invKn  = (double*)(ws + 35667968);          //     16,384 B -> 35,684,352
    float*  top8v  = (float*)(ws + 35684352);           //  1,048,576 B -> 36,732,928
    u16*    top8i  = (u16*)(ws + 36732928);             //    524,288 B -> 37,257,216
    u16*    S2     = (u16*)(ws + 67108864);             // 134,217,728 B bf16 scores

    prep_kernel<<<NB / 4 + NM / 4, 256, 0, stream>>>(x, xn, K, kn, invKn, s, logs, counts);
    gemm_kernel<<<1024, 512, 0, stream>>>(xn, kn, S2);
    candrefine_kernel<<<NB / 4, 256, 0, stream>>>(S2, x, K, invKn,
                                                  top8v, top8i, f_out, g_out, counts, attn);
    finalize_kernel<<<NB / 4, 256, 0, stream>>>(top8v, top8i, counts, logs, V,
                                                g_out, y, attn);
}